// Round 14
// baseline (49.488 us; speedup 1.0000x reference)
//
#include <hip/hip_runtime.h>
#include <hip/hip_bf16.h>

#define D_ 128
#define S_ 512
#define B_ 4
#define H_ 8

typedef short bf16x8 __attribute__((ext_vector_type(8)));
typedef unsigned int u32x4 __attribute__((ext_vector_type(4)));
typedef float f32x4 __attribute__((ext_vector_type(4)));
typedef float f32x2 __attribute__((ext_vector_type(2)));

__device__ __forceinline__ short f2bf(float f) {
  __hip_bfloat16 h = __float2bfloat16(f);
  return __builtin_bit_cast(short, h);
}
__device__ __forceinline__ float fsigmoid(float x) {
  return __builtin_amdgcn_rcpf(1.0f + __expf(-x));
}
// HW packed f32->bf16 (RNE) — verified in r9 staging path.
__device__ __forceinline__ unsigned int cvt_pk_bf16(float lo, float hi) {
  unsigned int r;
  asm("v_cvt_pk_bf16_f32 %0, %1, %2" : "=v"(r) : "v"(lo), "v"(hi));
  return r;
}

// Proj v4: r9-verbatim GEMM (verified). Aq stays f32 (edge apk path
// verbatim); Cq now stored as bf16 (cvt_pk_bf16, the instruction r9's
// staging used) so edge can read MFMA fragments directly from global.
__global__ __launch_bounds__(256)
void proj_kernel(const float* __restrict__ x, const float* __restrict__ w1,
                 const float* __restrict__ b1, float* __restrict__ Aq,
                 short* __restrict__ Cbf) {
  __shared__ float xs[4 * D_];
  __shared__ f32x4 red[256][5];
  const int t = threadIdx.x;
  const int row0 = blockIdx.x * 4;
  ((float2*)xs)[t] = ((const float2*)(x + row0 * D_))[t];
  __syncthreads();
  const int combo = t & 63;
  const int e4 = (combo & 31) * 4;
  const int half = combo >> 5;
  const int kq = t >> 6;
  const float* w1p = w1 + (half * D_ + kq * 32) * D_ + e4;
  const float* xq = xs + kq * 32;
  f32x4 acc[4] = {};
  #pragma unroll 8
  for (int k = 0; k < 32; ++k) {
    float4 wv = *(const float4*)(w1p + k * D_);
    #pragma unroll
    for (int r = 0; r < 4; ++r) {
      float xv = xq[r * D_ + k];
      acc[r][0] += xv * wv.x; acc[r][1] += xv * wv.y;
      acc[r][2] += xv * wv.z; acc[r][3] += xv * wv.w;
    }
  }
  #pragma unroll
  for (int r = 0; r < 4; ++r) red[t][r] = acc[r];
  __syncthreads();
  const int r = t >> 6;
  const int c2 = t & 63;
  f32x4 s = red[c2][r];
  #pragma unroll
  for (int q = 1; q < 4; ++q) {
    f32x4 v = red[c2 + 64 * q][r];
    s[0] += v[0]; s[1] += v[1]; s[2] += v[2]; s[3] += v[3];
  }
  const int fe4 = (c2 & 31) * 4;
  const int row = row0 + r;
  if ((c2 >> 5) == 0) {
    float4 bv = *(const float4*)(b1 + fe4);
    s[0] += bv.x; s[1] += bv.y; s[2] += bv.z; s[3] += bv.w;
    *(f32x4*)(Aq + row * D_ + fe4) = s;
  } else {
    uint2 u;
    u.x = cvt_pk_bf16(s[0], s[1]);
    u.y = cvt_pk_bf16(s[2], s[3]);
    *(uint2*)(Cbf + row * D_ + fe4) = u;
  }
}

// Edge v7: BISECT arm — r13's no-LDS/no-barrier structure with r9-verbatim
// verified numerics (bf16 fragments, bit-op unpack, pk_add_f32, cvt_pk_bf16,
// mfma bf16). C fragments read directly from L2-resident Cbf (64KB/(b,jh),
// shared by 64 blocks; r4 precedent proves global reads of proj output are
// safe). Isolates r13's f16 cluster as the failing component.
// MFMA A: row=lane&15 (=j), k=8*(lane>>4)+e. D: col=lane&15 (=h),
// row=(lane>>4)*4+reg. (verified r2-r11)
__global__ __launch_bounds__(512, 4)
void edge_kernel(const float* __restrict__ Aq, const short* __restrict__ Cbf,
                 const float* __restrict__ w2, const float* __restrict__ b2,
                 float* __restrict__ out) {
  const int t = threadIdx.x;
  const int lane = t & 63;
  const int wid = t >> 6;                // 0..7
  const int b  = blockIdx.x >> 7;
  const int jh = (blockIdx.x >> 6) & 1;  // j half
  const int ig = blockIdx.x & 63;
  const int i  = ig * 8 + wid;

  const int jcol = lane & 15;            // j within tile == output h
  const int lgrp = lane >> 4;            // k-group

  // a registers as packed f32x2 (b1 folded in proj) — r9 verbatim
  f32x2 apk[4][4];
  {
    const float* Ai = Aq + (b * S_ + i) * D_ + lgrp * 8;
    #pragma unroll
    for (int ch = 0; ch < 4; ++ch) {
      float4 v0 = *(const float4*)(Ai + ch * 32);
      float4 v1 = *(const float4*)(Ai + ch * 32 + 4);
      apk[ch][0][0] = v0.x; apk[ch][0][1] = v0.y;
      apk[ch][1][0] = v0.z; apk[ch][1][1] = v0.w;
      apk[ch][2][0] = v1.x; apk[ch][2][1] = v1.y;
      apk[ch][3][0] = v1.z; apk[ch][3][1] = v1.w;
    }
  }
  // w2 B-frags (bf16) — r9 verbatim
  bf16x8 w2f[4];
  #pragma unroll
  for (int ch = 0; ch < 4; ++ch) {
    #pragma unroll
    for (int e = 0; e < 8; ++e) {
      float wv = (jcol < H_) ? w2[(ch * 32 + lgrp * 8 + e) * H_ + jcol] : 0.0f;
      w2f[ch][e] = f2bf(wv);
    }
  }
  const float b2v = (jcol < H_) ? b2[jcol] : 0.0f;
  float* outp = out + (((size_t)(b * H_ + (jcol & 7)) * S_ + i) * S_)
                + jh * 256 + lgrp * 4;

  const short* Cb = Cbf + (b * S_ + jh * 256) * D_ + lgrp * 8;

  u32x4 cva[4], cvb[4];
  auto LOADT = [&](u32x4 (&dst)[4], int jt) {
    const short* bp = Cb + (jt * 16 + jcol) * D_;
    #pragma unroll
    for (int ch = 0; ch < 4; ++ch)
      dst[ch] = *(const u32x4*)(bp + ch * 32);
  };
  auto COMPUTE = [&](u32x4 (&cv)[4], int jt) {   // r9 verbatim
    f32x4 acc = {0.f, 0.f, 0.f, 0.f};
    #pragma unroll
    for (int ch = 0; ch < 4; ++ch) {
      u32x4 hfd;
      #pragma unroll
      for (int p = 0; p < 4; ++p) {
        unsigned int d = cv[ch][p];
        f32x2 v;
        v[0] = __builtin_bit_cast(float, d << 16);
        v[1] = __builtin_bit_cast(float, d & 0xffff0000u);
        v += apk[ch][p];
        hfd[p] = cvt_pk_bf16(fmaxf(v[0], 0.f), fmaxf(v[1], 0.f));
      }
      bf16x8 hf = __builtin_bit_cast(bf16x8, hfd);
      acc = __builtin_amdgcn_mfma_f32_16x16x32_bf16(hf, w2f[ch], acc, 0, 0, 0);
    }
    if (jcol < H_) {
      float4 o;
      o.x = fsigmoid(acc[0] + b2v);
      o.y = fsigmoid(acc[1] + b2v);
      o.z = fsigmoid(acc[2] + b2v);
      o.w = fsigmoid(acc[3] + b2v);
      *(float4*)(outp + jt * 16) = o;
    }
  };

  LOADT(cva, 0);
  #pragma unroll 1
  for (int jt = 0; jt < 16; jt += 2) {
    LOADT(cvb, jt + 1);
    COMPUTE(cva, jt);
    LOADT(cva, (jt + 2) & 15);           // wrap harmless (valid memory)
    COMPUTE(cvb, jt + 1);
  }
}

extern "C" void kernel_launch(void* const* d_in, const int* in_sizes, int n_in,
                              void* d_out, int out_size, void* d_ws, size_t ws_size,
                              hipStream_t stream) {
  const float* x  = (const float*)d_in[0];
  const float* w1 = (const float*)d_in[1];
  const float* b1 = (const float*)d_in[2];
  const float* w2 = (const float*)d_in[3];
  const float* b2 = (const float*)d_in[4];
  float* out = (float*)d_out;
  float* Aq  = (float*)d_ws;                // 2048*128 f32 = 1 MB
  short* Cbf = (short*)(Aq + B_ * S_ * D_); // + 512 KB bf16
  proj_kernel<<<(B_ * S_) / 4, 256, 0, stream>>>(x, w1, b1, Aq, Cbf);
  edge_kernel<<<B_ * 2 * 64, 512, 0, stream>>>(Aq, Cbf, w2, b2, out);
}